// Round 12
// baseline (280.677 us; speedup 1.0000x reference)
//
#include <hip/hip_runtime.h>
#include <math.h>

#define NN 100000
#define EE 1600000
#define ETOT (EE + NN)
#define NBUK 512
#define NPB 196        // nodes per bucket (512*196 >= NN)
#define CHUNK 3125     // 512*3125 == EE
#define CAP 6144       // LDS stage capacity per bucket (mean ~3332, +50 sigma)
#define GB 1563        // gemm blocks: ceil(NN/64)

typedef __attribute__((ext_vector_type(8))) short bf16x8;
typedef __attribute__((ext_vector_type(4))) float f32x4;

__device__ __forceinline__ unsigned short f2bf(float f) {
  unsigned int u = __float_as_uint(f);
  u = u + 0x7fffu + ((u >> 16) & 1u);  // RNE
  return (unsigned short)(u >> 16);
}

__device__ __forceinline__ float lrelu_exp(float e) {
  e = (e > 0.f) ? e : 0.2f * e;
  return __expf(e);
}

// One-shot: W (f32 [128k][128n]) -> padded bf16 Wt[n][136] in global.
// 8 blocks x 256 threads; thread (n, kg) converts 8 k-values, one 16B store.
__global__ __launch_bounds__(256) void k_wt(const float* __restrict__ W,
                                            unsigned short* __restrict__ Wtg) {
  int g = blockIdx.x * 256 + threadIdx.x;  // 2048 = 128 n x 16 kg
  int n = g >> 4, kg = g & 15;
  unsigned short tmp[8];
#pragma unroll
  for (int jj = 0; jj < 8; jj++) tmp[jj] = f2bf(W[(kg * 8 + jj) * 128 + n]);
  *((uint4*)&Wtg[n * 136 + kg * 8]) = *((const uint4*)tmp);
}

// Fused dispatch: blocks [0,GB) = MFMA bf16 GEMM + fused logits;
// blocks [GB, GB+NBUK) = P1 histogram + per-chunk bucket scan Sc (overlapped).
// W staging is now a pure coalesced uint4 copy of the precomputed bf16 Wt.
__global__ __launch_bounds__(256) void k_front(const float* __restrict__ x,
                                               const unsigned short* __restrict__ Wtg,
                                               const float* __restrict__ att_src,
                                               const float* __restrict__ att_dst,
                                               const int* __restrict__ ei,
                                               unsigned short* __restrict__ xwb,
                                               float* __restrict__ asrc,
                                               float* __restrict__ adst,
                                               int* __restrict__ H,
                                               int* __restrict__ Sc) {
  __shared__ __align__(16) unsigned short lds[17408];  // GEMM: Wt[128][136]; p1: scan scratch
  __shared__ float satt[256];
  __shared__ int hh[NBUK];
  int tid = threadIdx.x;

  if (blockIdx.x >= GB) {
    // ---- P1 role: per-(chunk,bucket) histogram + within-chunk exclusive scan ----
    int j = blockIdx.x - GB;
    for (int i = tid; i < NBUK; i += 256) hh[i] = 0;
    __syncthreads();
    int e0 = j * CHUNK;
    for (int e = e0 + tid; e < e0 + CHUNK; e += 256) {
      int d = ei[(size_t)EE + e];
      atomicAdd(&hh[d / NPB], 1);
    }
    __syncthreads();
    for (int i = tid; i < NBUK; i += 256) H[j * NBUK + i] = hh[i];
    // exclusive scan of hh[0..511] (two 256-halves) -> Sc[j][b]
    int* s = (int*)lds;
    int va = hh[tid], vb = hh[tid + 256];
    s[tid] = va;
    __syncthreads();
    for (int off = 1; off < 256; off <<= 1) {
      int tmp = (tid >= off) ? s[tid - off] : 0;
      __syncthreads();
      s[tid] += tmp;
      __syncthreads();
    }
    int Sa = s[tid], SaT = s[255];
    __syncthreads();
    s[tid] = vb;
    __syncthreads();
    for (int off = 1; off < 256; off <<= 1) {
      int tmp = (tid >= off) ? s[tid - off] : 0;
      __syncthreads();
      s[tid] += tmp;
      __syncthreads();
    }
    Sc[j * 512 + tid] = Sa - va;
    Sc[j * 512 + 256 + tid] = SaT + s[tid] - vb;
    return;
  }

  // ---- GEMM role: stage Wt by coalesced copy (2176 uint4 = 9 iters) ----
  for (int i = tid; i < 2176; i += 256)
    ((uint4*)lds)[i] = ((const uint4*)Wtg)[i];
  if (tid < 128) satt[tid] = att_src[tid];
  else satt[tid] = att_dst[tid - 128];
  __syncthreads();

  int wv = tid >> 6, lane = tid & 63;
  int m = lane & 15, q = lane >> 4;
  int r = blockIdx.x * 64 + wv * 16 + m;
  bool rok = (r < NN);

  bf16x8 af[4];
#pragma unroll
  for (int kt = 0; kt < 4; kt++) {
    float4 v0 = make_float4(0.f, 0.f, 0.f, 0.f), v1 = v0;
    if (rok) {
      v0 = ((const float4*)x)[(size_t)r * 32 + kt * 8 + q * 2];
      v1 = ((const float4*)x)[(size_t)r * 32 + kt * 8 + q * 2 + 1];
    }
    af[kt][0] = (short)f2bf(v0.x); af[kt][1] = (short)f2bf(v0.y);
    af[kt][2] = (short)f2bf(v0.z); af[kt][3] = (short)f2bf(v0.w);
    af[kt][4] = (short)f2bf(v1.x); af[kt][5] = (short)f2bf(v1.y);
    af[kt][6] = (short)f2bf(v1.z); af[kt][7] = (short)f2bf(v1.w);
  }

  f32x4 acc[8];
#pragma unroll
  for (int nt = 0; nt < 8; nt++) acc[nt] = (f32x4){0.f, 0.f, 0.f, 0.f};

#pragma unroll
  for (int nt = 0; nt < 8; nt++) {
#pragma unroll
    for (int kt = 0; kt < 4; kt++) {
      bf16x8 bf = *((const bf16x8*)&lds[(nt * 16 + m) * 136 + kt * 32 + q * 8]);
      acc[nt] = __builtin_amdgcn_mfma_f32_16x16x32_bf16(af[kt], bf, acc[nt], 0, 0, 0);
    }
  }

  __syncthreads();  // reuse LDS as output stage
#pragma unroll
  for (int nt = 0; nt < 8; nt++)
#pragma unroll
    for (int rg = 0; rg < 4; rg++)
      lds[(wv * 16 + q * 4 + rg) * 128 + nt * 16 + m] = f2bf(acc[nt][rg]);
  __syncthreads();

  size_t base = (size_t)blockIdx.x * 16384;
  const size_t lim = (size_t)NN * 256;
  for (int i = tid; i < 1024; i += 256) {
    size_t off = base + (size_t)i * 16;
    if (off < lim) *((uint4*)((char*)xwb + off)) = ((const uint4*)lds)[i];
  }

  int row = tid >> 2, h = tid & 3;
  int node = blockIdx.x * 64 + row;
  if (node < NN) {
    float ss = 0.f, sd = 0.f;
#pragma unroll
    for (int cq = 0; cq < 4; cq++) {
      uint4 u = *((const uint4*)&lds[row * 128 + h * 32 + cq * 8]);
      int cb = h * 32 + cq * 8;
      float f0 = __uint_as_float(u.x << 16), f1 = __uint_as_float(u.x & 0xffff0000u);
      float f2 = __uint_as_float(u.y << 16), f3 = __uint_as_float(u.y & 0xffff0000u);
      float f4 = __uint_as_float(u.z << 16), f5 = __uint_as_float(u.z & 0xffff0000u);
      float f6 = __uint_as_float(u.w << 16), f7 = __uint_as_float(u.w & 0xffff0000u);
      ss += f0 * satt[cb] + f1 * satt[cb + 1] + f2 * satt[cb + 2] + f3 * satt[cb + 3] +
            f4 * satt[cb + 4] + f5 * satt[cb + 5] + f6 * satt[cb + 6] + f7 * satt[cb + 7];
      sd += f0 * satt[128 + cb] + f1 * satt[128 + cb + 1] + f2 * satt[128 + cb + 2] +
            f3 * satt[128 + cb + 3] + f4 * satt[128 + cb + 4] + f5 * satt[128 + cb + 5] +
            f6 * satt[128 + cb + 6] + f7 * satt[128 + cb + 7];
    }
    asrc[(size_t)node * 4 + h] = ss;
    adst[(size_t)node * 4 + h] = sd;
  }
}

// Fused S1 || P3 (unchanged from round 11).
__global__ __launch_bounds__(256) void k_s1p3(const int* __restrict__ ei,
                                              const int* __restrict__ H,
                                              const int* __restrict__ Sc,
                                              int* __restrict__ R, int* __restrict__ T,
                                              int* __restrict__ tmpb) {
  __shared__ int sh[512 + CHUNK];
  int t = threadIdx.x;

  if (blockIdx.x < NBUK) {
    int b = blockIdx.x;
    int* s = sh;
    int va = H[t * NBUK + b];
    int vb = H[(t + 256) * NBUK + b];
    s[t] = va;
    __syncthreads();
    for (int off = 1; off < 256; off <<= 1) {
      int tmp = (t >= off) ? s[t - off] : 0;
      __syncthreads();
      s[t] += tmp;
      __syncthreads();
    }
    int Sa = s[t], SaT = s[255];
    __syncthreads();
    s[t] = vb;
    __syncthreads();
    for (int off = 1; off < 256; off <<= 1) {
      int tmp = (t >= off) ? s[t - off] : 0;
      __syncthreads();
      s[t] += tmp;
      __syncthreads();
    }
    R[b * 512 + t] = Sa - va;
    R[b * 512 + 256 + t] = SaT + s[t] - vb;
    if (t == 255) T[b] = SaT + s[255];
    return;
  }

  int j = blockIdx.x - NBUK;
  int* cur = sh;
  int* stage2 = sh + 512;
  for (int b2 = t; b2 < NBUK; b2 += 256) cur[b2] = Sc[j * 512 + b2];
  __syncthreads();
  int e0 = j * CHUNK;
  for (int e = e0 + t; e < e0 + CHUNK; e += 256) {
    int sv = ei[e];
    int dv = ei[(size_t)EE + e];
    int b2 = dv / NPB;
    int li = dv - b2 * NPB;
    int pos = atomicAdd(&cur[b2], 1);
    stage2[pos] = (li << 17) | sv;
  }
  __syncthreads();
  for (int i = t; i < CHUNK; i += 256) tmpb[(size_t)j * CHUNK + i] = stage2[i];
}

// P4 (+inline S2) — unchanged from round 11.
__global__ __launch_bounds__(256) void k_p4(const int* __restrict__ tmpb,
                                            const int* __restrict__ H,
                                            const int* __restrict__ R,
                                            const int* __restrict__ T,
                                            const int* __restrict__ Sc,
                                            int* __restrict__ es, int* __restrict__ offs) {
  __shared__ int raw[CAP];
  __shared__ int stage[CAP];
  __shared__ int cnt[256];
  __shared__ int curn[NPB];
  int b = blockIdx.x, t = threadIdx.x;
  if (b == 0 && t == 0) offs[NN] = ETOT;
  int n0 = b * NPB;
  int nloc = NN - n0;
  if (nloc <= 0) return;
  if (nloc > NPB) nloc = NPB;
  int total = T[b];
  int pacc = 0;
  for (int i = t; i < b; i += 256) pacc += T[i];
  cnt[t] = pacc;
  __syncthreads();
  for (int off = 128; off; off >>= 1) {
    if (t < off) cnt[t] += cnt[t + off];
    __syncthreads();
  }
  int bs = cnt[0] + n0;
  __syncthreads();
  cnt[t] = (t < nloc) ? 1 : 0;
  __syncthreads();
  for (int jj = t; jj < 512; jj += 256) {
    int st = Sc[jj * 512 + b];
    int ln = H[jj * NBUK + b];
    int rb = R[b * 512 + jj];
    const int* src = tmpb + (size_t)jj * CHUNK + st;
    for (int k = 0; k < ln; k++) {
      int w = src[k];
      int p = rb + k;
      if (p < CAP) raw[p] = w;
      atomicAdd(&cnt[w >> 17], 1);
    }
  }
  __syncthreads();
  int v = cnt[t];
  __syncthreads();
  for (int off = 1; off < 256; off <<= 1) {
    int tmp = (t >= off) ? cnt[t - off] : 0;
    __syncthreads();
    cnt[t] += tmp;
    __syncthreads();
  }
  int excl = cnt[t] - v;
  if (t < nloc) {
    offs[n0 + t] = bs + excl;
    curn[t] = excl + 1;
    if (excl < CAP) stage[excl] = n0 + t;
  }
  __syncthreads();
  int tl = (total < CAP) ? total : CAP;
  for (int e = t; e < tl; e += 256) {
    int u = raw[e];
    int pos = atomicAdd(&curn[u >> 17], 1);
    if (pos < CAP) stage[pos] = u & 0x1FFFF;
  }
  __syncthreads();
  int btot = total + nloc;
  if (btot > CAP) btot = CAP;
  for (int i = t; i < btot; i += 256) es[bs + i] = stage[i];
}

// one wave per destination node: 16-edge batches, all masked-full-width.
// Exp dedup: 16 edges x 4 heads = 64 slots = one lane each (lane l owns edge
// l>>2, head l&3); weight via __shfl(wl, i*4+h). 16 gathers in flight (named
// scalars, no arrays). In-register denominator; 4-int4 es prefetch.
__global__ __launch_bounds__(256) void k_agg(const unsigned short* __restrict__ xwb,
                                             const float* __restrict__ asrc,
                                             const float* __restrict__ adst,
                                             const int* __restrict__ offs,
                                             const int* __restrict__ es,
                                             const float* __restrict__ bias,
                                             const float* __restrict__ gamma,
                                             const float* __restrict__ beta,
                                             float* __restrict__ out) {
  int lane = threadIdx.x & 63;
  int node = blockIdx.x * 4 + (threadIdx.x >> 6);
  int off0 = offs[node];
  int d = offs[node + 1] - off0;
  int h = lane >> 4;   // head for channel accumulation (c = lane*2)
  int he = lane & 3;   // head for this lane's exp duty
  int sel = lane >> 2; // this lane's exp-duty edge within a 16-batch
  int c = lane * 2;

  float4 ad4 = *((const float4*)(adst + (size_t)node * 4));
  float ade = (he & 2) ? ((he & 1) ? ad4.w : ad4.z) : ((he & 1) ? ad4.y : ad4.x);

  const unsigned* xp = (const unsigned*)xwb + lane;
  const int* ep = es + off0;
  float ax0 = 0.f, ay0 = 0.f, ax1 = 0.f, ay1 = 0.f;
  float wsum = 0.f;

  int nb = (d + 15) >> 4;  // >= 1 (self-loop)
  int4 qa = *((const int4*)(ep));
  int4 qb = *((const int4*)(ep + 4));
  int4 qc = *((const int4*)(ep + 8));
  int4 qd = *((const int4*)(ep + 12));

  for (int b = 0; b < nb; ++b) {
    int4 na = *((const int4*)(ep + (b + 1) * 16));
    int4 nb2 = *((const int4*)(ep + (b + 1) * 16 + 4));
    int4 nc2 = *((const int4*)(ep + (b + 1) * 16 + 8));
    int4 nd2 = *((const int4*)(ep + (b + 1) * 16 + 12));

    int base = b * 16;
    int s0 = qa.x, s1 = qa.y, s2 = qa.z, s3 = qa.w;
    int s4 = qb.x, s5 = qb.y, s6 = qb.z, s7 = qb.w;
    int s8 = qc.x, s9 = qc.y, s10 = qc.z, s11 = qc.w;
    int s12 = qd.x, s13 = qd.y, s14 = qd.z, s15 = qd.w;
    bool full = (base + 16 <= d);
    if (!full) {  // wave-uniform clamp of out-of-range slots
      s0 = (base + 0 < d) ? s0 : 0;   s1 = (base + 1 < d) ? s1 : 0;
      s2 = (base + 2 < d) ? s2 : 0;   s3 = (base + 3 < d) ? s3 : 0;
      s4 = (base + 4 < d) ? s4 : 0;   s5 = (base + 5 < d) ? s5 : 0;
      s6 = (base + 6 < d) ? s6 : 0;   s7 = (base + 7 < d) ? s7 : 0;
      s8 = (base + 8 < d) ? s8 : 0;   s9 = (base + 9 < d) ? s9 : 0;
      s10 = (base + 10 < d) ? s10 : 0; s11 = (base + 11 < d) ? s11 : 0;
      s12 = (base + 12 < d) ? s12 : 0; s13 = (base + 13 < d) ? s13 : 0;
      s14 = (base + 14 < d) ? s14 : 0; s15 = (base + 15 < d) ? s15 : 0;
    }
    // exp-duty source: direct load (wave-uniform row, L2-hot), clamped for safety
    int se = ep[base + sel];
    if ((unsigned)se >= (unsigned)NN) se = 0;
    float av = asrc[(size_t)(unsigned)se * 4u + (unsigned)he];

    unsigned u0 = xp[(unsigned)s0 * 64u];
    unsigned u1 = xp[(unsigned)s1 * 64u];
    unsigned u2 = xp[(unsigned)s2 * 64u];
    unsigned u3 = xp[(unsigned)s3 * 64u];
    unsigned u4 = xp[(unsigned)s4 * 64u];
    unsigned u5 = xp[(unsigned)s5 * 64u];
    unsigned u6 = xp[(unsigned)s6 * 64u];
    unsigned u7 = xp[(unsigned)s7 * 64u];
    unsigned u8 = xp[(unsigned)s8 * 64u];
    unsigned u9 = xp[(unsigned)s9 * 64u];
    unsigned u10 = xp[(unsigned)s10 * 64u];
    unsigned u11 = xp[(unsigned)s11 * 64u];
    unsigned u12 = xp[(unsigned)s12 * 64u];
    unsigned u13 = xp[(unsigned)s13 * 64u];
    unsigned u14 = xp[(unsigned)s14 * 64u];
    unsigned u15 = xp[(unsigned)s15 * 64u];

    float wl = lrelu_exp(av + ade);
    float w0 = __shfl(wl, 0 * 4 + h);
    float w1 = __shfl(wl, 1 * 4 + h);
    float w2 = __shfl(wl, 2 * 4 + h);
    float w3 = __shfl(wl, 3 * 4 + h);
    float w4 = __shfl(wl, 4 * 4 + h);
    float w5 = __shfl(wl, 5 * 4 + h);
    float w6 = __shfl(wl, 6 * 4 + h);
    float w7 = __shfl(wl, 7 * 4 + h);
    float w8 = __shfl(wl, 8 * 4 + h);
    float w9 = __shfl(wl, 9 * 4 + h);
    float w10 = __shfl(wl, 10 * 4 + h);
    float w11 = __shfl(wl, 11 * 4 + h);
    float w12 = __shfl(wl, 12 * 4 + h);
    float w13 = __shfl(wl, 13 * 4 + h);
    float w14 = __shfl(wl, 14 * 4 + h);
    float w15 = __shfl(wl, 15 * 4 + h);
    if (!full) {
      w0 = (base + 0 < d) ? w0 : 0.f;   w1 = (base + 1 < d) ? w1 : 0.f;
      w2 = (base + 2 < d) ? w2 : 0.f;   w3 = (base + 3 < d) ? w3 : 0.f;
      w4 = (base + 4 < d) ? w4 : 0.f;   w5 = (base + 5 < d) ? w5 : 0.f;
      w6 = (base + 6 < d) ? w6 : 0.f;   w7 = (base + 7 < d) ? w7 : 0.f;
      w8 = (base + 8 < d) ? w8 : 0.f;   w9 = (base + 9 < d) ? w9 : 0.f;
      w10 = (base + 10 < d) ? w10 : 0.f; w11 = (base + 11 < d) ? w11 : 0.f;
      w12 = (base + 12 < d) ? w12 : 0.f; w13 = (base + 13 < d) ? w13 : 0.f;
      w14 = (base + 14 < d) ? w14 : 0.f; w15 = (base + 15 < d) ? w15 : 0.f;
    }
    wsum += (((w0 + w1) + (w2 + w3)) + ((w4 + w5) + (w6 + w7))) +
            (((w8 + w9) + (w10 + w11)) + ((w12 + w13) + (w14 + w15)));
    ax0 = fmaf(w0, __uint_as_float(u0 << 16), ax0);
    ay0 = fmaf(w0, __uint_as_float(u0 & 0xffff0000u), ay0);
    ax1 = fmaf(w1, __uint_as_float(u1 << 16), ax1);
    ay1 = fmaf(w1, __uint_as_float(u1 & 0xffff0000u), ay1);
    ax0 = fmaf(w2, __uint_as_float(u2 << 16), ax0);
    ay0 = fmaf(w2, __uint_as_float(u2 & 0xffff0000u), ay0);
    ax1 = fmaf(w3, __uint_as_float(u3 << 16), ax1);
    ay1 = fmaf(w3, __uint_as_float(u3 & 0xffff0000u), ay1);
    ax0 = fmaf(w4, __uint_as_float(u4 << 16), ax0);
    ay0 = fmaf(w4, __uint_as_float(u4 & 0xffff0000u), ay0);
    ax1 = fmaf(w5, __uint_as_float(u5 << 16), ax1);
    ay1 = fmaf(w5, __uint_as_float(u5 & 0xffff0000u), ay1);
    ax0 = fmaf(w6, __uint_as_float(u6 << 16), ax0);
    ay0 = fmaf(w6, __uint_as_float(u6 & 0xffff0000u), ay0);
    ax1 = fmaf(w7, __uint_as_float(u7 << 16), ax1);
    ay1 = fmaf(w7, __uint_as_float(u7 & 0xffff0000u), ay1);
    ax0 = fmaf(w8, __uint_as_float(u8 << 16), ax0);
    ay0 = fmaf(w8, __uint_as_float(u8 & 0xffff0000u), ay0);
    ax1 = fmaf(w9, __uint_as_float(u9 << 16), ax1);
    ay1 = fmaf(w9, __uint_as_float(u9 & 0xffff0000u), ay1);
    ax0 = fmaf(w10, __uint_as_float(u10 << 16), ax0);
    ay0 = fmaf(w10, __uint_as_float(u10 & 0xffff0000u), ay0);
    ax1 = fmaf(w11, __uint_as_float(u11 << 16), ax1);
    ay1 = fmaf(w11, __uint_as_float(u11 & 0xffff0000u), ay1);
    ax0 = fmaf(w12, __uint_as_float(u12 << 16), ax0);
    ay0 = fmaf(w12, __uint_as_float(u12 & 0xffff0000u), ay0);
    ax1 = fmaf(w13, __uint_as_float(u13 << 16), ax1);
    ay1 = fmaf(w13, __uint_as_float(u13 & 0xffff0000u), ay1);
    ax0 = fmaf(w14, __uint_as_float(u14 << 16), ax0);
    ay0 = fmaf(w14, __uint_as_float(u14 & 0xffff0000u), ay0);
    ax1 = fmaf(w15, __uint_as_float(u15 << 16), ax1);
    ay1 = fmaf(w15, __uint_as_float(u15 & 0xffff0000u), ay1);

    qa = na; qb = nb2; qc = nc2; qd = nd2;
  }

  float accx = ax0 + ax1, accy = ay0 + ay1;
  float rn = 1.f / (wsum + 1e-16f);

  float vx = accx * rn + bias[c];
  float vy = accy * rn + bias[c + 1];
  float sum = vx + vy, sq = vx * vx + vy * vy;
#pragma unroll
  for (int o = 32; o; o >>= 1) {
    sum += __shfl_xor(sum, o);
    sq += __shfl_xor(sq, o);
  }
  float mean = sum * (1.f / 128.f);
  float var = sq * (1.f / 128.f) - mean * mean;
  float rs = rsqrtf(var + 1e-5f);
  float o0 = gamma[c] * (vx - mean) * rs + beta[c];
  float o1 = gamma[c + 1] * (vy - mean) * rs + beta[c + 1];
  float2 ov; ov.x = o0; ov.y = o1;
  *((float2*)(out + (size_t)node * 128 + c)) = ov;
}

extern "C" void kernel_launch(void* const* d_in, const int* in_sizes, int n_in,
                              void* d_out, int out_size, void* d_ws, size_t ws_size,
                              hipStream_t stream) {
  const float* x = (const float*)d_in[0];
  const int* ei = (const int*)d_in[1];  // int32 per harness contract
  const float* W = (const float*)d_in[3];
  const float* att_src = (const float*)d_in[4];
  const float* att_dst = (const float*)d_in[5];
  const float* bias = (const float*)d_in[6];
  const float* gamma = (const float*)d_in[7];
  const float* beta = (const float*)d_in[8];
  float* out = (float*)d_out;

  char* p = (char*)d_ws;
  auto alloc = [&](size_t bytes) -> char* {
    char* r = p;
    p += (bytes + 255) & ~(size_t)255;
    return r;
  };
  unsigned short* xwb = (unsigned short*)alloc((size_t)NN * 128 * 2);  // 25.6 MB
  float* asrc = (float*)alloc((size_t)NN * 4 * 4);                     // 1.6 MB
  float* adst = (float*)alloc((size_t)NN * 4 * 4);                     // 1.6 MB
  int* es = (int*)alloc((size_t)ETOT * 4 + 256);                       // 6.8 MB + slack
  int* offs = (int*)alloc((size_t)(NN + 1) * 4);
  int* tmpb = (int*)alloc((size_t)EE * 4);                             // 6.4 MB, chunk-major
  int* H = (int*)alloc((size_t)512 * NBUK * 4);                        // 1 MB
  int* Sc = (int*)alloc((size_t)512 * NBUK * 4);                       // 1 MB
  int* R = (int*)alloc((size_t)NBUK * 512 * 4);                        // 1 MB
  int* T = (int*)alloc((size_t)NBUK * 4);
  unsigned short* Wtg = (unsigned short*)alloc((size_t)128 * 136 * 2); // 34.8 KB

  k_wt<<<8, 256, 0, stream>>>(W, Wtg);
  k_front<<<GB + NBUK, 256, 0, stream>>>(x, Wtg, att_src, att_dst, ei, xwb, asrc, adst, H, Sc);
  k_s1p3<<<2 * NBUK, 256, 0, stream>>>(ei, H, Sc, R, T, tmpb);
  k_p4<<<NBUK, 256, 0, stream>>>(tmpb, H, R, T, Sc, es, offs);
  k_agg<<<NN / 4, 256, 0, stream>>>(xwb, asrc, adst, offs, es, bias, gamma, beta, out);
}